// Round 3
// baseline (274.660 us; speedup 1.0000x reference)
//
#include <hip/hip_runtime.h>

// Problem constants: x is (256, 3, 224, 224) float32.
#define N_IMG   256
#define HW      (224 * 224)        // 50176
#define CHW     (3 * HW)           // 150528 floats per image
#define V4      (CHW / 4)          // 37632 float4 per image = 256 * 147
#define THREADS 256

// Both kernels: 21 chunks * (7 float4/thread * 256 threads) = 37632 = V4
#define CHUNKS      21
#define CHUNK_V4    (V4 / CHUNKS)          // 1792
#define PER_THREAD  (CHUNK_V4 / THREADS)   // 7

#define MAGS_PER_TF 9

// Native clang vector type — required for __builtin_nontemporal_store
typedef float fvec4 __attribute__((ext_vector_type(4)));

__device__ __forceinline__ float clip01(float v) {
    return fminf(fmaxf(v, 0.0f), 1.0f);
}

// Kernel 1: per-image mean partials — only for images that actually need the
// mean (tf_idx == 1 (contrast) AND apply_mask[sample] > 0). Other blocks exit
// immediately; their partial slots stay poisoned but are never read.
__global__ __launch_bounds__(THREADS) void mean_kernel(
        const float* __restrict__ x,
        const int* __restrict__ sample,
        const int* __restrict__ apply_mask,
        float* __restrict__ partials /* [N_IMG][CHUNKS] */) {
    const int img  = blockIdx.y;
    const int part = blockIdx.x;
    const int s    = sample[img];
    if ((s / MAGS_PER_TF) != 1 || apply_mask[s] <= 0) return;

    const fvec4* xp = (const fvec4*)x + (size_t)img * V4 + (size_t)part * CHUNK_V4;
    fvec4 v[PER_THREAD];
#pragma unroll
    for (int k = 0; k < PER_THREAD; ++k)
        v[k] = xp[threadIdx.x + k * THREADS];

    float sum = 0.0f;
#pragma unroll
    for (int k = 0; k < PER_THREAD; ++k)
        sum += (v[k].x + v[k].y) + (v[k].z + v[k].w);

    // wave (64-lane) shuffle reduction
#pragma unroll
    for (int off = 32; off > 0; off >>= 1)
        sum += __shfl_down(sum, off, 64);

    __shared__ float wsum[THREADS / 64];
    if ((threadIdx.x & 63) == 0) wsum[threadIdx.x >> 6] = sum;
    __syncthreads();
    if (threadIdx.x == 0) {
        float t = (wsum[0] + wsum[1]) + (wsum[2] + wsum[3]);
        partials[img * CHUNKS + part] = t;
    }
}

// Kernel 2: elementwise transform. 7 float4 per thread, all loads issued
// before compute (MLP=7). Whole block works on one image -> wave-uniform
// branch, zero divergence. Nontemporal stores: output is write-once.
__global__ __launch_bounds__(THREADS) void apply_kernel(
        const float* __restrict__ x,
        const int* __restrict__ sample,
        const int* __restrict__ apply_mask,
        const float* __restrict__ partials,
        float* __restrict__ out) {
    const int img   = blockIdx.y;
    const int chunk = blockIdx.x;
    const int s     = sample[img];
    const int tf    = s / MAGS_PER_TF;
    const float mag = (float)(s % MAGS_PER_TF + 1) / 10.0f;
    const bool applied = apply_mask[s] > 0;

    const size_t base = (size_t)img * V4 + (size_t)chunk * CHUNK_V4 + threadIdx.x;
    const fvec4* xp = (const fvec4*)x + base;
    fvec4*       op = (fvec4*)out + base;

    fvec4 v[PER_THREAD];
#pragma unroll
    for (int k = 0; k < PER_THREAD; ++k)
        v[k] = xp[k * THREADS];

    fvec4 r[PER_THREAD];

    if (!applied) {
#pragma unroll
        for (int k = 0; k < PER_THREAD; ++k) r[k] = v[k];
    } else if (tf == 0) {            // brightness: clip(x + mag)
#pragma unroll
        for (int k = 0; k < PER_THREAD; ++k) {
            r[k].x = clip01(v[k].x + mag);
            r[k].y = clip01(v[k].y + mag);
            r[k].z = clip01(v[k].z + mag);
            r[k].w = clip01(v[k].w + mag);
        }
    } else if (tf == 1) {            // contrast: clip(mean + (x-mean)*(1+mag))
        float mean = 0.0f;
#pragma unroll
        for (int p = 0; p < CHUNKS; ++p) mean += partials[img * CHUNKS + p];
        mean /= (float)CHW;
        const float g = 1.0f + mag;
#pragma unroll
        for (int k = 0; k < PER_THREAD; ++k) {
            r[k].x = clip01(mean + (v[k].x - mean) * g);
            r[k].y = clip01(mean + (v[k].y - mean) * g);
            r[k].z = clip01(mean + (v[k].z - mean) * g);
            r[k].w = clip01(mean + (v[k].w - mean) * g);
        }
    } else if (tf == 2) {            // invert-lerp: (1-mag)*x + mag*(1-x), NO clip
        const float a = 1.0f - mag;
#pragma unroll
        for (int k = 0; k < PER_THREAD; ++k) {
            r[k].x = a * v[k].x + mag * (1.0f - v[k].x);
            r[k].y = a * v[k].y + mag * (1.0f - v[k].y);
            r[k].z = a * v[k].z + mag * (1.0f - v[k].z);
            r[k].w = a * v[k].w + mag * (1.0f - v[k].w);
        }
    } else {                         // gain: clip(x * (1+mag))
        const float g = 1.0f + mag;
#pragma unroll
        for (int k = 0; k < PER_THREAD; ++k) {
            r[k].x = clip01(v[k].x * g);
            r[k].y = clip01(v[k].y * g);
            r[k].z = clip01(v[k].z * g);
            r[k].w = clip01(v[k].w * g);
        }
    }

#pragma unroll
    for (int k = 0; k < PER_THREAD; ++k)
        __builtin_nontemporal_store(r[k], op + k * THREADS);
}

extern "C" void kernel_launch(void* const* d_in, const int* in_sizes, int n_in,
                              void* d_out, int out_size, void* d_ws, size_t ws_size,
                              hipStream_t stream) {
    const float* x          = (const float*)d_in[0];
    const int*   sample     = (const int*)d_in[1];
    const int*   apply_mask = (const int*)d_in[2];
    float*       out        = (float*)d_out;
    float*       partials   = (float*)d_ws;   // N_IMG * CHUNKS floats = 21 KiB

    dim3 mgrid(CHUNKS, N_IMG);
    mean_kernel<<<mgrid, THREADS, 0, stream>>>(x, sample, apply_mask, partials);

    dim3 agrid(CHUNKS, N_IMG);
    apply_kernel<<<agrid, THREADS, 0, stream>>>(x, sample, apply_mask, partials, out);
}